// Round 8
// baseline (3346.074 us; speedup 1.0000x reference)
//
#include <hip/hip_runtime.h>
#include <stdint.h>

// ---- problem constants ----
#define NB   32        // batch
#define NCH  128       // num atoms
#define IMG  64
#define IMG2 4096      // 64*64
#define OH   57        // 64-8+1
#define OHW  3249      // 57*57
#define CHW  415872    // 128*3249 (per-sample code size)
#define KTOP 256       // sparsity K
#define NATT 17        // alphas 2^0 .. 2^-16 (while count<=15 semantics)
#define NS   32        // candidate counter slices per sample (atomic spread)
#define SCAP 512       // capacity per slice
#define NCAP 1536      // collected (non-support) cap in suppg phase
#define NBUCK 8192     // |g| histogram buckets (top 13 bits: sign+exp8+mant4)
#define HSHIFT 18      // bits >> 18 -> bucket
#define TGT  512       // keep at least top-512 of |g| (superset of top-256 non-support)
#define RSTRIDE 72     // recon LDS row stride (2-way banks, free)
#define BMW  12996     // bitmap words for CHW bits (415872/32)
#define CSBLK 102      // collect blocks per sample (102*1024 >= CHW/4)

typedef unsigned long long ull;

// ---------------- init (once per replay): zero hist + counters ----------------
__global__ __launch_bounds__(256) void k_init(
    uint32_t* __restrict__ hist, int* __restrict__ cand_cnt,
    int* __restrict__ done_cnt, int* __restrict__ done_cnt2,
    int* __restrict__ support_cnt)
{
    int bx = blockIdx.x, tid = threadIdx.x;
    if (bx < 256) {
        ((uint4*)hist)[bx * 256 + tid] = make_uint4(0u, 0u, 0u, 0u);
    } else {
        // cand_cnt = NB*NS = 1024 ints = 256 uint4  (R6 bug: only 64 were zeroed)
        ((uint4*)cand_cnt)[tid] = make_uint4(0u, 0u, 0u, 0u);
        if (tid < NB) { done_cnt[tid] = 0; done_cnt2[tid] = 0; support_cnt[tid] = 0; }
    }
}

// ---------------- mega-conv: update + residual rebuild + D^T*R + hist + thresh ----
// Grid (NB,16) x 256. Each block: (t>0) redundantly picks a_sel and loads the
// selected support into LDS; rebuilds the residual tile Rs itself (kills k_resid);
// cg0==0 blocks write sup_iv/support_cnt/l2cur. Then the verified FMA+hist phase.
// Last-finishing block per sample computes thr[b] and self-cleans hist/done_cnt.
__global__ __launch_bounds__(256) void k_conv2(
    const float* __restrict__ Y, const float* __restrict__ W,
    const double* __restrict__ l2prev, const double* __restrict__ errv,
    const uint32_t* __restrict__ sel_idx, const float* __restrict__ sel_val, int t,
    int* __restrict__ support_cnt, ull* __restrict__ sup_iv,
    float* __restrict__ g_out, uint32_t* __restrict__ hist,
    int* __restrict__ done_cnt, uint32_t* __restrict__ thr,
    double* __restrict__ l2cur)
{
    int b = blockIdx.x, cg0 = blockIdx.y, tid = threadIdx.x;
    int lane = tid & 63, wid = tid >> 6;
    __shared__ float Rs[71 * 72];
    __shared__ uint32_t hl[NBUCK];
    __shared__ double redl2[256];
    __shared__ uint32_t s_si[KTOP];
    __shared__ float s_sv[KTOP];
    __shared__ int a_sh, elect_sh;

    for (int i = tid; i < 71 * 72; i += 256) Rs[i] = 0.f;
    for (int i = tid; i < NBUCK; i += 256) hl[i] = 0u;

    int n = 0;
    if (t > 0) {
        // redundant a_sel pick (all blocks agree: same doubles, same order)
        if (tid < NATT) {
            double e = 0.0;
#pragma unroll 8
            for (int b2 = 0; b2 < NB; ++b2) e += errv[tid * NB + b2];
            redl2[tid] = e;
        } else if (tid == NATT) {
            double l2 = 0.0;
#pragma unroll 8
            for (int b2 = 0; b2 < NB; ++b2) l2 += l2prev[b2];
            redl2[NATT] = l2;
        }
        __syncthreads();
        if (tid == 0) {
            double l2 = redl2[NATT];
            int sel = NATT - 1;
            for (int a2 = 0; a2 < NATT; ++a2) if (redl2[a2] < l2) { sel = a2; break; }
            a_sh = sel;
        }
        __syncthreads();
        int a = a_sh;
        size_t o = ((size_t)a * NB + b) * KTOP;
        uint32_t mi = sel_idx[o + tid];
        float mv = sel_val[o + tid];
        s_si[tid] = mi;
        s_sv[tid] = mv;
        if (cg0 == 0) {
            sup_iv[b * KTOP + tid] = (ull)mi | ((ull)__float_as_uint(mv) << 32);
            if (tid == 0) support_cnt[b] = KTOP;
        }
        n = KTOP;
    }
    __syncthreads();   // barrier 1: Rs zeroed, s_si/s_sv visible

    // Y into the 64x64 region of Rs (stride 72)
    const float4* Y4 = (const float4*)(Y + b * IMG2);
    for (int i = tid; i < 1024; i += 256) {
        int row = i >> 4, col4 = (i & 15) * 4;
        *(float4*)&Rs[row * 72 + col4] = Y4[i];
    }
    __syncthreads();   // barrier 2: Y staged

    // sparse support scatter: R -= val * atom
    for (int task = tid; task < n * 64; task += 256) {
        int i = task >> 6, tap = task & 63, p = tap >> 3, q = tap & 7;
        uint32_t idx = s_si[i];
        float val = s_sv[i];
        int c = idx / OHW, rem = idx % OHW, s = rem / OH, tt = rem % OH;
        float w = W[c * 64 + p * 8 + q];
        atomicAdd(&Rs[(s + p) * 72 + (tt + q)], -val * w);
    }
    __syncthreads();   // barrier 3: residual complete

    // l2 of residual (padding cols/rows are zero -> full-tile sum is exact)
    {
        double acc = 0.0;
        for (int i = tid; i < 71 * 72; i += 256) { float v = Rs[i]; acc += (double)v * (double)v; }
        for (int d = 32; d > 0; d >>= 1) acc += __shfl_xor(acc, d, 64);
        if (lane == 0) redl2[wid] = acc;
        __syncthreads();
        if (cg0 == 0 && tid == 0) l2cur[b] = redl2[0] + redl2[1] + redl2[2] + redl2[3];
    }

    // ---- FMA phase (verbatim) ----
    int csub = tid >> 7;
    int tile = tid & 127;
    bool active = tile < 120;
    int tr = active ? tile / 15 : 0;
    int tc = active ? tile % 15 : 0;
    int s0 = tr * 8, t0 = tc * 4;

    for (int sub = 0; sub < 4; ++sub) {
        int c = cg0 * 8 + sub * 2 + csub;
        int c_s = __builtin_amdgcn_readfirstlane(c);
        const float* Wc = W + c_s * 64;

        float acc[8][4];
#pragma unroll
        for (int r = 0; r < 8; ++r)
#pragma unroll
            for (int cc = 0; cc < 4; ++cc) acc[r][cc] = 0.f;

#pragma unroll
        for (int rho = 0; rho < 15; ++rho) {
            float rb[12];
            const float* rp = &Rs[(s0 + rho) * 72 + t0];
            *(float4*)&rb[0] = *(const float4*)rp;
            *(float4*)&rb[4] = *(const float4*)(rp + 4);
            *(float4*)&rb[8] = *(const float4*)(rp + 8);
#pragma unroll
            for (int r = 0; r < 8; ++r) {
                const int p = rho - r;
                if (p >= 0 && p < 8) {
#pragma unroll
                    for (int q = 0; q < 8; ++q) {
                        float wv = Wc[q * 8 + p];
#pragma unroll
                        for (int cc = 0; cc < 4; ++cc)
                            acc[r][cc] = fmaf(rb[cc + q], wv, acc[r][cc]);
                    }
                }
            }
        }
        if (active) {
            float* go = g_out + (size_t)(b * NCH + c) * OHW;
#pragma unroll
            for (int r = 0; r < 8; ++r) {
                int s = s0 + r;
                if (s < OH) {
#pragma unroll
                    for (int cc = 0; cc < 4; ++cc) {
                        int tcol = t0 + cc;
                        if (tcol < OH) {
                            float v = acc[r][cc];
                            go[s * OH + tcol] = v;
                            uint32_t bits = __float_as_uint(v) & 0x7fffffffu;
                            atomicAdd(&hl[bits >> HSHIFT], 1u);
                        }
                    }
                }
            }
        }
    }
    __syncthreads();
    for (int i = tid; i < NBUCK; i += 256) {
        uint32_t v = hl[i];
        if (v) atomicAdd(&hist[b * NBUCK + i], v);
    }
    __syncthreads();
    if (tid == 0) {
        __threadfence();
        int old = atomicAdd(&done_cnt[b], 1);
        elect_sh = (old == 15) ? 1 : 0;
    }
    __syncthreads();
    if (elect_sh) {
        // ---- thresh body (verbatim logic) ----
        uint32_t h[32];
        uint32_t s = 0;
        const uint32_t* hb = hist + b * NBUCK + tid * 32;
#pragma unroll
        for (int k = 0; k < 32; ++k) {
            h[k] = __hip_atomic_load(&hb[k], __ATOMIC_RELAXED, __HIP_MEMORY_SCOPE_AGENT);
            s += h[k];
        }
        uint32_t* buf0 = hl;
        uint32_t* buf1 = hl + 256;
        int cur = 0;
        buf0[tid] = s;
        __syncthreads();
        for (int d = 1; d < 256; d <<= 1) {
            uint32_t* bc = cur ? buf1 : buf0;
            uint32_t* bn = cur ? buf0 : buf1;
            uint32_t v = bc[tid];
            if (tid + d < 256) v += bc[tid + d];
            bn[tid] = v;
            cur ^= 1;
            __syncthreads();
        }
        uint32_t* bc = cur ? buf1 : buf0;
        uint32_t sufme = bc[tid];
        uint32_t base  = (tid < 255) ? bc[tid + 1] : 0u;
        if (tid == 0 && bc[0] < TGT) thr[b] = 0u;
        if (base < TGT && sufme >= TGT) {
            uint32_t acc2 = base; int bk = 0;
#pragma unroll
            for (int k = 31; k >= 0; --k) {
                acc2 += h[k];
                if (acc2 >= TGT) { bk = tid * 32 + k; break; }
            }
            thr[b] = (uint32_t)bk << HSHIFT;
        }
        __syncthreads();
        // self-clean for next iteration (visible via dispatch-boundary release)
        for (int i = tid; i < NBUCK / 4; i += 256)
            ((uint4*)(hist + (size_t)b * NBUCK))[i] = make_uint4(0u, 0u, 0u, 0u);
        if (tid == 0) done_cnt[b] = 0;
    }
}

// ---------------- fused collect + suppg (last-block election) ----------------
__global__ __launch_bounds__(1024) void k_collsuppg(
    const float* __restrict__ g, const uint32_t* __restrict__ thr,
    const int* __restrict__ support_cnt, const ull* __restrict__ sup_iv,
    int* __restrict__ cand_cnt, uint32_t* __restrict__ cand_idx, float* __restrict__ cand_g,
    uint4* __restrict__ ns_pack, ull* __restrict__ sup_gp, ull* __restrict__ kb_all,
    int* __restrict__ done_cnt2)
{
    int bx = blockIdx.x, b = blockIdx.y, tid = threadIdx.x, lane = tid & 63;
    __shared__ uint32_t bm[BMW];
    __shared__ int cnts[NS];
    __shared__ ull ck[NCAP];
    __shared__ float cg_l[NCAP];
    __shared__ int nns_sh, elect_sh;

    // ---- collect phase: one float4-strip per thread ----
    {
        int i4 = bx * 1024 + tid;
        if (i4 < CHW / 4) {
            int slice = bx & (NS - 1);
            uint32_t tb = thr[b];
            float4 v4 = ((const float4*)(g + (size_t)b * CHW))[i4];
            float vv[4] = { v4.x, v4.y, v4.z, v4.w };
#pragma unroll
            for (int k = 0; k < 4; ++k) {
                uint32_t bits = __float_as_uint(vv[k]) & 0x7fffffffu;
                if (bits >= tb) {
                    int pos = atomicAdd(&cand_cnt[b * NS + slice], 1);
                    if (pos >= 0 && pos < SCAP) {
                        // agent-scoped stores: coherent for the elected reader within this dispatch
                        __hip_atomic_store(&cand_idx[(b * NS + slice) * SCAP + pos],
                                           (uint32_t)(i4 * 4 + k), __ATOMIC_RELAXED, __HIP_MEMORY_SCOPE_AGENT);
                        __hip_atomic_store((uint32_t*)&cand_g[(b * NS + slice) * SCAP + pos],
                                           __float_as_uint(vv[k]), __ATOMIC_RELAXED, __HIP_MEMORY_SCOPE_AGENT);
                    }
                }
            }
        }
    }
    __threadfence();
    __syncthreads();
    if (tid == 0) {
        int old = atomicAdd(&done_cnt2[b], 1);
        elect_sh = (old == (int)gridDim.x - 1) ? 1 : 0;
    }
    __syncthreads();
    if (!elect_sh) return;
    __threadfence();

    // ---- suppg body (verbatim, with agent-scoped candidate reads) ----
    int n = support_cnt[b];
    for (int i = tid; i < BMW / 4; i += 1024) ((uint4*)bm)[i] = make_uint4(0u, 0u, 0u, 0u);
    if (tid < NS) {
        int cv = __hip_atomic_load(&cand_cnt[b * NS + tid], __ATOMIC_RELAXED,
                                   __HIP_MEMORY_SCOPE_AGENT);
        cnts[tid] = min(max(cv, 0), SCAP);
    }
    if (tid == 0) nns_sh = 0;
    __syncthreads();
    if (tid < KTOP) {
        float gv = 0.f, vs = 0.f;
        uint32_t nidx;
        if (tid < n) {
            ull iv = sup_iv[b * KTOP + tid];
            uint32_t idx = (uint32_t)iv;
            nidx = idx;
            vs = __uint_as_float((uint32_t)(iv >> 32));
            atomicOr(&bm[idx >> 5], 1u << (idx & 31));
            gv = g[(size_t)b * CHW + idx];
            int c = idx / OHW, r = idx % OHW, s = r / OH, t = r % OH;
            uint32_t pk = (uint32_t)((c << 12) | (s << 6) | t);
            sup_gp[b * KTOP + tid] = ((ull)__float_as_uint(gv) << 32) | (ull)pk;
        } else {
            nidx = (uint32_t)(CHW + tid);
            sup_gp[b * KTOP + tid] = 0ull;
        }
        ull klo = (ull)(uint32_t)(~nidx);
#pragma unroll
        for (int a2 = 0; a2 < NATT; ++a2) {
            float v2 = (tid < n) ? fmaf(ldexpf(1.f, -a2), gv, vs) : 0.f;
            kb_all[((size_t)a2 * NB + b) * KTOP + tid] =
                ((ull)(__float_as_uint(v2) & 0x7fffffffu) << 32) | klo;
        }
    }
    __syncthreads();
    for (int t0 = tid; t0 < NS * SCAP; t0 += 1024) {
        int s = t0 >> 9, j = t0 & (SCAP - 1);
        bool keep = false; uint32_t idx = 0; float gv = 0.f;
        if (j < cnts[s]) {
            idx = __hip_atomic_load(&cand_idx[(b * NS + s) * SCAP + j],
                                    __ATOMIC_RELAXED, __HIP_MEMORY_SCOPE_AGENT);
            gv = __uint_as_float(__hip_atomic_load((uint32_t*)&cand_g[(b * NS + s) * SCAP + j],
                                    __ATOMIC_RELAXED, __HIP_MEMORY_SCOPE_AGENT));
            keep = (idx < CHW) && (((bm[idx >> 5] >> (idx & 31)) & 1u) == 0u);
        }
        ull mk = __ballot(keep);
        if (mk) {
            int basep = 0;
            if (lane == 0) basep = atomicAdd(&nns_sh, (int)__popcll(mk));
            basep = __shfl(basep, 0, 64);
            if (keep) {
                int p = basep + (int)__popcll(mk & ((1ull << lane) - 1ull));
                if (p < NCAP) {
                    ck[p] = ((ull)(__float_as_uint(gv) & 0x7fffffffu) << 32) | (ull)(uint32_t)(~idx);
                    cg_l[p] = gv;
                }
            }
        }
    }
    __syncthreads();
    int nns = min(nns_sh, NCAP);
    int nns8 = (nns + 7) & ~7;
    for (int i = nns + tid; i < nns8; i += 1024) ck[i] = 0ull;
    __syncthreads();
    ull myk[2]; int myr[2];
#pragma unroll
    for (int q = 0; q < 2; ++q) { int i = tid + 1024 * q; myk[q] = (i < nns) ? ck[i] : 0ull; myr[q] = 0; }
    for (int j = 0; j < nns8; j += 8) {
        ull t0 = ck[j], t1 = ck[j+1], t2 = ck[j+2], t3 = ck[j+3];
        ull t4 = ck[j+4], t5 = ck[j+5], t6 = ck[j+6], t7 = ck[j+7];
#pragma unroll
        for (int q = 0; q < 2; ++q) {
            myr[q] += ((t0 > myk[q]) ? 1 : 0) + ((t1 > myk[q]) ? 1 : 0)
                    + ((t2 > myk[q]) ? 1 : 0) + ((t3 > myk[q]) ? 1 : 0)
                    + ((t4 > myk[q]) ? 1 : 0) + ((t5 > myk[q]) ? 1 : 0)
                    + ((t6 > myk[q]) ? 1 : 0) + ((t7 > myk[q]) ? 1 : 0);
        }
    }
#pragma unroll
    for (int q = 0; q < 2; ++q) {
        int i = tid + 1024 * q;
        if (i < nns && myr[q] < KTOP) {
            uint32_t idx = ~(uint32_t)myk[q];
            int r = myr[q];
            int c = idx / OHW, rr = idx % OHW, s = rr / OH, t = rr % OH;
            uint32_t pk = (uint32_t)((c << 12) | (s << 6) | t);
            ns_pack[b * KTOP + r] = make_uint4(idx, __float_as_uint(cg_l[i]), pk, 0u);
        }
    }
    // self-clean for next iteration
    __syncthreads();
    if (tid < NS) cand_cnt[b * NS + tid] = 0;
    if (tid == 0) done_cnt2[b] = 0;
}

// ---------------- fused attempt: selection + recon + err (R2-exact) + out-zero ----
__global__ __launch_bounds__(512) void k_att2(
    const float* __restrict__ Y, const float* __restrict__ W,
    const int* __restrict__ support_cnt, const ull* __restrict__ sup_iv,
    const ull* __restrict__ sup_gp, const uint4* __restrict__ ns_pack,
    const ull* __restrict__ kb_all,
    uint32_t* __restrict__ sel_idx, float* __restrict__ sel_val, double* __restrict__ err,
    float* __restrict__ outz, int zf)
{
    int a = blockIdx.x, b = blockIdx.y, tid = threadIdx.x;
    int lane = tid & 63, wid = tid >> 6;
    float alpha = ldexpf(1.f, -a);
    int n = support_cnt[b];

    __shared__ float recon[64 * RSTRIDE];  // 18 KB
    __shared__ ull kA[KTOP];
    __shared__ ull s_pv[KTOP];             // lo32 = pk, hi32 = val bits (by rank)
    __shared__ uint32_t s_idx[KTOP];
    __shared__ double redd[8];

    uint32_t myi = 0, mypk = 0;
    float myv = 0.f;
    ull myk = 0;
    if (tid < KTOP) {
        uint4 np = ns_pack[b * KTOP + tid];
        myi = np.x;
        myv = alpha * __uint_as_float(np.y);
        mypk = np.z;
        myk = ((ull)(__float_as_uint(myv) & 0x7fffffffu) << 32) | (ull)(uint32_t)(~myi);
        kA[tid] = myk;
    } else {
        int t2 = tid - KTOP;
        ull gp = sup_gp[b * KTOP + t2];
        ull iv = sup_iv[b * KTOP + t2];
        if (t2 < n) {
            myi = (uint32_t)iv;
            myv = fmaf(alpha, __uint_as_float((uint32_t)(gp >> 32)),
                       __uint_as_float((uint32_t)(iv >> 32)));
            mypk = (uint32_t)gp;
        } else {
            myi = (uint32_t)(CHW + t2);
            myv = 0.f; mypk = 0u;
        }
        myk = ((ull)(__float_as_uint(myv) & 0x7fffffffu) << 32) | (ull)(uint32_t)(~myi);
    }

    const float4* Y4 = (const float4*)(Y + b * IMG2);
    float4 y0 = Y4[tid * 2], y1 = Y4[tid * 2 + 1];

    for (int i = tid; i < 64 * RSTRIDE; i += 512) recon[i] = 0.f;
    __syncthreads();

    const ull* __restrict__ kb = kb_all + ((size_t)a * NB + b) * KTOP;
    int cb0 = 0, cb1 = 0;
    for (int j = 0; j < KTOP; j += 8) {
        ull t0 = kb[j],     t1 = kb[j + 1], t2 = kb[j + 2], t3 = kb[j + 3];
        ull t4 = kb[j + 4], t5 = kb[j + 5], t6 = kb[j + 6], t7 = kb[j + 7];
        cb0 += ((t0 > myk) ? 1 : 0) + ((t1 > myk) ? 1 : 0)
             + ((t2 > myk) ? 1 : 0) + ((t3 > myk) ? 1 : 0);
        cb1 += ((t4 > myk) ? 1 : 0) + ((t5 > myk) ? 1 : 0)
             + ((t6 > myk) ? 1 : 0) + ((t7 > myk) ? 1 : 0);
    }
    int cb = cb0 + cb1;
    int rank;
    if (tid < KTOP) {
        rank = tid + cb;
    } else {
        int lo = 0, hi = KTOP;
        while (lo < hi) { int mid = (lo + hi) >> 1; if (kA[mid] > myk) lo = mid + 1; else hi = mid; }
        rank = lo + cb;
    }
    if (rank < KTOP) {
        s_pv[rank] = ((ull)__float_as_uint(myv) << 32) | (ull)mypk;
        s_idx[rank] = myi;
    }
    __syncthreads();

    {
        int p = lane >> 3, q = lane & 7;
        ull pv[4]; float wv[4];
#pragma unroll
        for (int j = 0; j < 4; ++j) pv[j] = s_pv[wid + 8 * j];
#pragma unroll
        for (int j = 0; j < 4; ++j) wv[j] = W[(((uint32_t)pv[j]) >> 12) * 64 + lane];
#pragma unroll
        for (int k4 = 0; k4 < 32; k4 += 4) {
            ull npv[4] = {0, 0, 0, 0}; float nwv[4] = {0.f, 0.f, 0.f, 0.f};
            if (k4 + 4 < 32) {
#pragma unroll
                for (int j = 0; j < 4; ++j) npv[j] = s_pv[wid + 8 * (k4 + 4 + j)];
#pragma unroll
                for (int j = 0; j < 4; ++j) nwv[j] = W[(((uint32_t)npv[j]) >> 12) * 64 + lane];
            }
#pragma unroll
            for (int j = 0; j < 4; ++j) {
                uint32_t pk = (uint32_t)pv[j];
                float val = __uint_as_float((uint32_t)(pv[j] >> 32));
                int s = (pk >> 6) & 63, t = pk & 63;
                atomicAdd(&recon[(s + p) * RSTRIDE + (t + q)], val * wv[j]);
            }
#pragma unroll
            for (int j = 0; j < 4; ++j) { pv[j] = npv[j]; wv[j] = nwv[j]; }
        }
    }
    __syncthreads();

    double accd = 0.0;
    {
        int idx0 = tid * 2;
        const float* rr = &recon[(idx0 >> 4) * RSTRIDE + (idx0 & 15) * 4];
        float d0 = y0.x - rr[0]; accd += (double)d0 * (double)d0;
        float d1 = y0.y - rr[1]; accd += (double)d1 * (double)d1;
        float d2 = y0.z - rr[2]; accd += (double)d2 * (double)d2;
        float d3 = y0.w - rr[3]; accd += (double)d3 * (double)d3;
        int idx1 = tid * 2 + 1;
        rr = &recon[(idx1 >> 4) * RSTRIDE + (idx1 & 15) * 4];
        float e0 = y1.x - rr[0]; accd += (double)e0 * (double)e0;
        float e1 = y1.y - rr[1]; accd += (double)e1 * (double)e1;
        float e2 = y1.z - rr[2]; accd += (double)e2 * (double)e2;
        float e3 = y1.w - rr[3]; accd += (double)e3 * (double)e3;
    }
    for (int d = 32; d > 0; d >>= 1) accd += __shfl_xor(accd, d, 64);
    if (lane == 0) redd[wid] = accd;
    __syncthreads();
    if (tid == 0) {
        double e = 0.0;
#pragma unroll
        for (int w2 = 0; w2 < 8; ++w2) e += redd[w2];
        err[a * NB + b] = e;
    }

    if (tid < KTOP) {
        size_t o = ((size_t)a * NB + b) * KTOP;
        ull pvt = s_pv[tid];
        sel_idx[o + tid] = s_idx[tid];
        sel_val[o + tid] = __uint_as_float((uint32_t)(pvt >> 32));
    }

    // fused out-zero on the final iteration (att2 never reads g/out)
    if (zf) {
        float4* o4 = (float4*)outz;
        size_t fb = (size_t)a * NB + b;
        for (size_t i = fb * 512 + tid; i < (size_t)NB * CHW / 4; i += (size_t)NATT * NB * 512)
            o4[i] = make_float4(0.f, 0.f, 0.f, 0.f);
    }
}

// ---------------- final: fused alpha-select + scatter ----------------
__global__ __launch_bounds__(256) void k_scatter2(
    const double* __restrict__ l2f, const double* __restrict__ errv,
    const uint32_t* __restrict__ sel_idx, const float* __restrict__ sel_val,
    float* __restrict__ out)
{
    int b = blockIdx.x, tid = threadIdx.x;
    __shared__ double red2[NATT + 1];
    __shared__ int a_sh;
    if (tid < NATT) {
        double e = 0.0;
#pragma unroll 8
        for (int b2 = 0; b2 < NB; ++b2) e += errv[tid * NB + b2];
        red2[tid] = e;
    } else if (tid == NATT) {
        double l2 = 0.0;
#pragma unroll 8
        for (int b2 = 0; b2 < NB; ++b2) l2 += l2f[b2];
        red2[NATT] = l2;
    }
    __syncthreads();
    if (tid == 0) {
        double l2 = red2[NATT];
        int sel = NATT - 1;
        for (int a2 = 0; a2 < NATT; ++a2) if (red2[a2] < l2) { sel = a2; break; }
        a_sh = sel;
    }
    __syncthreads();
    size_t o = ((size_t)a_sh * NB + b) * KTOP;
    out[(size_t)b * CHW + sel_idx[o + tid]] = sel_val[o + tid];
}

// ---------------- host ----------------
static size_t align256(size_t x) { return (x + 255) & ~(size_t)255; }

extern "C" void kernel_launch(void* const* d_in, const int* in_sizes, int n_in,
                              void* d_out, int out_size, void* d_ws, size_t ws_size,
                              hipStream_t stream)
{
    const float* Y = (const float*)d_in[0];   // (32,1,64,64)
    const float* W = (const float*)d_in[1];   // (128,1,8,8), normalized
    float* out = (float*)d_out;               // (32,128,57,57) — doubles as dense g

    char* p = (char*)d_ws;
    size_t off = 0;
    auto carve = [&](size_t bytes) { void* r = p + off; off = align256(off + bytes); return r; };
    uint32_t* hist        = (uint32_t*)carve((size_t)NB * NBUCK * sizeof(uint32_t));
    uint32_t* thr         = (uint32_t*)carve(NB * sizeof(uint32_t));
    int*      cand_cnt    = (int*)     carve(NB * NS * sizeof(int));
    int*      done_cnt    = (int*)     carve(NB * sizeof(int));
    int*      done_cnt2   = (int*)     carve(NB * sizeof(int));
    double*   l2part      = (double*)  carve(2 * NB * sizeof(double));
    double*   err         = (double*)  carve((size_t)NATT * NB * sizeof(double));
    int*      support_cnt = (int*)     carve(NB * sizeof(int));
    ull*      sup_iv      = (ull*)     carve((size_t)NB * KTOP * sizeof(ull));
    uint32_t* sel_idx     = (uint32_t*)carve((size_t)NATT * NB * KTOP * sizeof(uint32_t));
    float*    sel_val     = (float*)   carve((size_t)NATT * NB * KTOP * sizeof(float));
    uint32_t* cand_idx    = (uint32_t*)carve((size_t)NB * NS * SCAP * sizeof(uint32_t));
    float*    cand_g      = (float*)   carve((size_t)NB * NS * SCAP * sizeof(float));
    uint4*    ns_pack     = (uint4*)   carve((size_t)NB * KTOP * sizeof(uint4));
    ull*      sup_gp      = (ull*)     carve((size_t)NB * KTOP * sizeof(ull));
    ull*      kb_all      = (ull*)     carve((size_t)NATT * NB * KTOP * sizeof(ull));
    (void)ws_size; (void)in_sizes; (void)n_in; (void)out_size;

    k_init<<<257, 256, 0, stream>>>(hist, cand_cnt, done_cnt, done_cnt2, support_cnt);
    for (int t = 0; t < 3; ++t) {
        double* l2cur  = l2part + (t & 1) * NB;
        double* l2prev = l2part + ((t + 1) & 1) * NB;
        k_conv2<<<dim3(NB, 16), 256, 0, stream>>>(Y, W, l2prev, err, sel_idx, sel_val, t,
                                                  support_cnt, sup_iv, out, hist,
                                                  done_cnt, thr, l2cur);
        k_collsuppg<<<dim3(CSBLK, NB), 1024, 0, stream>>>(out, thr, support_cnt, sup_iv,
                                                          cand_cnt, cand_idx, cand_g,
                                                          ns_pack, sup_gp, kb_all, done_cnt2);
        k_att2<<<dim3(NATT, NB), 512, 0, stream>>>(Y, W, support_cnt, sup_iv,
                                                   sup_gp, ns_pack, kb_all,
                                                   sel_idx, sel_val, err,
                                                   out, (t == 2) ? 1 : 0);
    }
    // final selection fused into scatter; l2 of iter 2 lives in buffer (2&1)=0
    k_scatter2<<<NB, 256, 0, stream>>>(l2part, err, sel_idx, sel_val, out);
}

// Round 9
// 642.397 us; speedup vs baseline: 5.2087x; 5.2087x over previous
//
#include <hip/hip_runtime.h>
#include <stdint.h>

// ---- problem constants ----
#define NB   32        // batch
#define NCH  128       // num atoms
#define IMG  64
#define IMG2 4096      // 64*64
#define OH   57        // 64-8+1
#define OHW  3249      // 57*57
#define CHW  415872    // 128*3249 (per-sample code size)
#define KTOP 256       // sparsity K
#define NATT 17        // alphas 2^0 .. 2^-16 (while count<=15 semantics)
#define NS   32        // candidate counter slices per sample (atomic spread)
#define SCAP 512       // capacity per slice
#define NCAP 1536      // collected (non-support) cap in k_suppg
#define NBUCK 8192     // |g| histogram buckets (top 13 bits: sign+exp8+mant4)
#define HSHIFT 18      // bits >> 18 -> bucket
#define TGT  512       // keep at least top-512 of |g| (superset of top-256 non-support)
#define RSTRIDE 72     // recon LDS row stride (2-way banks, free)
#define NZB  257       // zero-blocks fused into k_resid (256 hist + 1 cand_cnt)
#define BMW  12996     // bitmap words for CHW bits (415872/32)

typedef unsigned long long ull;

// ---------------- init: support count = 0 ----------------
__global__ void k_init(int* support_cnt) {
    if (threadIdx.x < NB) support_cnt[threadIdx.x] = 0;
}

// ---------------- fused: adopt prev attempt + R = Y - D*X + zeroing ----------------
// Blocks 0..NB-1: (t>0) pick a_sel from prev err/l2 (cross-dispatch reads: safe),
// copy sel[a_sel] as new support, sparse-scatter residual from LDS. Blocks NB..:
// zero hist + cand_cnt for this iteration. NO intra-dispatch cross-block traffic.
__global__ __launch_bounds__(256) void k_resid(
    const float* __restrict__ Y, const float* __restrict__ W,
    const double* __restrict__ l2prev, const double* __restrict__ errv,
    const uint32_t* __restrict__ sel_idx, const float* __restrict__ sel_val, int t,
    int* __restrict__ support_cnt, ull* __restrict__ sup_iv,
    float* __restrict__ Rg, double* __restrict__ l2cur,
    uint32_t* __restrict__ hist, int* __restrict__ cand_cnt)
{
    int bx = blockIdx.x, tid = threadIdx.x;
    if (bx >= NB) {
        int zb = bx - NB;
        if (zb < 256) {
            ((uint4*)hist)[zb * 256 + tid] = make_uint4(0u, 0u, 0u, 0u);
        } else {
            ((uint4*)cand_cnt)[tid] = make_uint4(0u, 0u, 0u, 0u);  // 256 uint4 = 1024 ints
        }
        return;
    }
    int b = bx;
    __shared__ float Rs[IMG2];
    __shared__ uint32_t s_si[KTOP];
    __shared__ float s_sv[KTOP];
    __shared__ double red[256];
    __shared__ int a_sh;

    const float4* Y4 = (const float4*)(Y + b * IMG2);
    float4* R4 = (float4*)Rs;
    for (int i = tid; i < IMG2 / 4; i += 256) R4[i] = Y4[i];

    int n = 0;
    if (t > 0) {
        // ---- update phase: pick first alpha with err < l2_start (prev iter) ----
        if (tid < NATT) {
            double e = 0.0;
#pragma unroll 8
            for (int b2 = 0; b2 < NB; ++b2) e += errv[tid * NB + b2];
            red[tid] = e;
        } else if (tid == NATT) {
            double l2 = 0.0;
#pragma unroll 8
            for (int b2 = 0; b2 < NB; ++b2) l2 += l2prev[b2];
            red[NATT] = l2;
        }
        __syncthreads();
        if (tid == 0) {
            double l2 = red[NATT];
            int sel = NATT - 1;
            for (int a2 = 0; a2 < NATT; ++a2) if (red[a2] < l2) { sel = a2; break; }
            a_sh = sel;
        }
        __syncthreads();
        int a = a_sh;
        size_t o = ((size_t)a * NB + b) * KTOP;
        uint32_t mi = sel_idx[o + tid];
        float mv = sel_val[o + tid];
        s_si[tid] = mi;
        s_sv[tid] = mv;
        sup_iv[b * KTOP + tid] = (ull)mi | ((ull)__float_as_uint(mv) << 32);
        if (tid == 0) support_cnt[b] = KTOP;
        n = KTOP;
    }
    __syncthreads();   // Rs + selection visible

    for (int task = tid; task < n * 64; task += 256) {
        int i = task >> 6, tap = task & 63, p = tap >> 3, q = tap & 7;
        uint32_t idx = s_si[i];
        float val = s_sv[i];
        int c = idx / OHW, rem = idx % OHW, s = rem / OH, tt = rem % OH;
        float w = W[c * 64 + p * 8 + q];
        atomicAdd(&Rs[(s + p) * IMG + (tt + q)], -val * w);
    }
    __syncthreads();
    double acc = 0.0;
    for (int i = tid; i < IMG2; i += 256) {
        float v = Rs[i];
        Rg[b * IMG2 + i] = v;
        acc += (double)v * (double)v;
    }
    red[tid] = acc; __syncthreads();
    for (int s2 = 128; s2 > 0; s2 >>= 1) { if (tid < s2) red[tid] += red[tid + s2]; __syncthreads(); }
    if (tid == 0) l2cur[b] = red[0];
}

// ---------------- g = D^T * R (dense) + fine |g| histogram ----------------
__global__ __launch_bounds__(256) void k_conv(
    const float* __restrict__ Rg, const float* __restrict__ W,
    float* __restrict__ g_out, uint32_t* __restrict__ hist)
{
    int b = blockIdx.x, cg0 = blockIdx.y, tid = threadIdx.x;
    __shared__ float Rs[71 * 72];
    __shared__ uint32_t hl[NBUCK];
    for (int i = tid; i < 71 * 72; i += 256) Rs[i] = 0.f;
    for (int i = tid; i < NBUCK; i += 256) hl[i] = 0u;
    __syncthreads();
    const float4* R4 = (const float4*)(Rg + b * IMG2);
    for (int i = tid; i < 1024; i += 256) {
        int row = i >> 4, col4 = (i & 15) * 4;
        *(float4*)&Rs[row * 72 + col4] = R4[i];
    }
    __syncthreads();
    int csub = tid >> 7;
    int tile = tid & 127;
    bool active = tile < 120;
    int tr = active ? tile / 15 : 0;
    int tc = active ? tile % 15 : 0;
    int s0 = tr * 8, t0 = tc * 4;

    for (int sub = 0; sub < 4; ++sub) {
        int c = cg0 * 8 + sub * 2 + csub;
        int c_s = __builtin_amdgcn_readfirstlane(c);
        const float* Wc = W + c_s * 64;

        float acc[8][4];
#pragma unroll
        for (int r = 0; r < 8; ++r)
#pragma unroll
            for (int cc = 0; cc < 4; ++cc) acc[r][cc] = 0.f;

#pragma unroll
        for (int rho = 0; rho < 15; ++rho) {
            float rb[12];
            const float* rp = &Rs[(s0 + rho) * 72 + t0];
            *(float4*)&rb[0] = *(const float4*)rp;
            *(float4*)&rb[4] = *(const float4*)(rp + 4);
            *(float4*)&rb[8] = *(const float4*)(rp + 8);
#pragma unroll
            for (int r = 0; r < 8; ++r) {
                const int p = rho - r;
                if (p >= 0 && p < 8) {
#pragma unroll
                    for (int q = 0; q < 8; ++q) {
                        float wv = Wc[q * 8 + p];
#pragma unroll
                        for (int cc = 0; cc < 4; ++cc)
                            acc[r][cc] = fmaf(rb[cc + q], wv, acc[r][cc]);
                    }
                }
            }
        }
        if (active) {
            float* go = g_out + (size_t)(b * NCH + c) * OHW;
#pragma unroll
            for (int r = 0; r < 8; ++r) {
                int s = s0 + r;
                if (s < OH) {
#pragma unroll
                    for (int cc = 0; cc < 4; ++cc) {
                        int tcol = t0 + cc;
                        if (tcol < OH) {
                            float v = acc[r][cc];
                            go[s * OH + tcol] = v;
                            uint32_t bits = __float_as_uint(v) & 0x7fffffffu;
                            atomicAdd(&hl[bits >> HSHIFT], 1u);
                        }
                    }
                }
            }
        }
    }
    __syncthreads();
    for (int i = tid; i < NBUCK; i += 256) {
        uint32_t v = hl[i];
        if (v) atomicAdd(&hist[b * NBUCK + i], v);
    }
}

// ---------------- per-sample bucket threshold (parallel suffix scan) ----------------
__global__ __launch_bounds__(256) void k_thresh(const uint32_t* __restrict__ hist,
                                                uint32_t* __restrict__ thr) {
    int b = blockIdx.x, tid = threadIdx.x;
    uint32_t h[32];
    uint32_t s = 0;
    const uint32_t* hb = hist + b * NBUCK + tid * 32;
#pragma unroll
    for (int k = 0; k < 32; ++k) { h[k] = hb[k]; s += h[k]; }
    __shared__ uint32_t buf[2][256];
    int cur = 0;
    buf[0][tid] = s;
    __syncthreads();
    for (int d = 1; d < 256; d <<= 1) {
        uint32_t v = buf[cur][tid];
        if (tid + d < 256) v += buf[cur][tid + d];
        buf[cur ^ 1][tid] = v;
        cur ^= 1;
        __syncthreads();
    }
    uint32_t sufme = buf[cur][tid];
    uint32_t base  = (tid < 255) ? buf[cur][tid + 1] : 0u;
    if (tid == 0 && buf[cur][0] < TGT) thr[b] = 0u;
    if (base < TGT && sufme >= TGT) {
        uint32_t acc = base; int bk = 0;
#pragma unroll
        for (int k = 31; k >= 0; --k) {
            acc += h[k];
            if (acc >= TGT) { bk = tid * 32 + k; break; }
        }
        thr[b] = (uint32_t)bk << HSHIFT;
    }
}

// ---------------- collect candidates: |g| above bucket threshold ----------------
__global__ __launch_bounds__(256) void k_collect(
    const float* __restrict__ g, const uint32_t* __restrict__ thr,
    int* __restrict__ cand_cnt, uint32_t* __restrict__ cand_idx, float* __restrict__ cand_g)
{
    int b = blockIdx.y;
    int i4 = blockIdx.x * 256 + threadIdx.x;
    if (i4 >= CHW / 4) return;
    int slice = blockIdx.x & (NS - 1);
    uint32_t tb = thr[b];
    float4 v4 = ((const float4*)(g + (size_t)b * CHW))[i4];
    float vv[4] = { v4.x, v4.y, v4.z, v4.w };
#pragma unroll
    for (int k = 0; k < 4; ++k) {
        uint32_t bits = __float_as_uint(vv[k]) & 0x7fffffffu;
        if (bits >= tb) {
            int pos = atomicAdd(&cand_cnt[b * NS + slice], 1);
            if (pos < SCAP) {
                cand_idx[(b * NS + slice) * SCAP + pos] = (uint32_t)(i4 * 4 + k);
                cand_g[(b * NS + slice) * SCAP + pos] = vv[k];
            }
        }
    }
}

// ---------------- build per-sample pools + per-alpha support keys ----------------
__global__ __launch_bounds__(1024) void k_suppg(
    const float* __restrict__ g,
    const int* __restrict__ support_cnt, const ull* __restrict__ sup_iv,
    const int* __restrict__ cand_cnt, const uint32_t* __restrict__ cand_idx,
    const float* __restrict__ cand_g,
    uint4* __restrict__ ns_pack, ull* __restrict__ sup_gp, ull* __restrict__ kb_all)
{
    int b = blockIdx.x, tid = threadIdx.x, lane = tid & 63;
    __shared__ uint32_t bm[BMW];
    __shared__ int cnts[NS];
    __shared__ ull ck[NCAP];
    __shared__ float cg_l[NCAP];
    __shared__ int nns_sh;
    int n = support_cnt[b];
    for (int i = tid; i < BMW / 4; i += 1024) ((uint4*)bm)[i] = make_uint4(0u, 0u, 0u, 0u);
    if (tid < NS) cnts[tid] = min(cand_cnt[b * NS + tid], SCAP);
    if (tid == 0) nns_sh = 0;
    __syncthreads();
    if (tid < KTOP) {
        float gv = 0.f, vs = 0.f;
        uint32_t nidx;
        if (tid < n) {
            ull iv = sup_iv[b * KTOP + tid];
            uint32_t idx = (uint32_t)iv;
            nidx = idx;
            vs = __uint_as_float((uint32_t)(iv >> 32));
            atomicOr(&bm[idx >> 5], 1u << (idx & 31));
            gv = g[(size_t)b * CHW + idx];
            int c = idx / OHW, r = idx % OHW, s = r / OH, t = r % OH;
            uint32_t pk = (uint32_t)((c << 12) | (s << 6) | t);
            sup_gp[b * KTOP + tid] = ((ull)__float_as_uint(gv) << 32) | (ull)pk;
        } else {
            nidx = (uint32_t)(CHW + tid);
            sup_gp[b * KTOP + tid] = 0ull;
        }
        // per-alpha support keys: identical bit pattern to what k_att2 computes
        ull klo = (ull)(uint32_t)(~nidx);
#pragma unroll
        for (int a2 = 0; a2 < NATT; ++a2) {
            float v2 = (tid < n) ? fmaf(ldexpf(1.f, -a2), gv, vs) : 0.f;
            kb_all[((size_t)a2 * NB + b) * KTOP + tid] =
                ((ull)(__float_as_uint(v2) & 0x7fffffffu) << 32) | klo;
        }
    }
    __syncthreads();
    for (int t0 = tid; t0 < NS * SCAP; t0 += 1024) {
        int s = t0 >> 9, j = t0 & (SCAP - 1);
        bool keep = false; uint32_t idx = 0; float gv = 0.f;
        if (j < cnts[s]) {
            idx = cand_idx[(b * NS + s) * SCAP + j];
            gv = cand_g[(b * NS + s) * SCAP + j];
            keep = ((bm[idx >> 5] >> (idx & 31)) & 1u) == 0u;
        }
        ull mk = __ballot(keep);
        if (mk) {
            int basep = 0;
            if (lane == 0) basep = atomicAdd(&nns_sh, (int)__popcll(mk));
            basep = __shfl(basep, 0, 64);
            if (keep) {
                int p = basep + (int)__popcll(mk & ((1ull << lane) - 1ull));
                if (p < NCAP) {
                    ck[p] = ((ull)(__float_as_uint(gv) & 0x7fffffffu) << 32) | (ull)(uint32_t)(~idx);
                    cg_l[p] = gv;
                }
            }
        }
    }
    __syncthreads();
    int nns = min(nns_sh, NCAP);
    int nns8 = (nns + 7) & ~7;          // zero-pad so the rank loop runs in groups of 8
    for (int i = nns + tid; i < nns8; i += 1024) ck[i] = 0ull;
    __syncthreads();
    ull myk[2]; int myr[2];
#pragma unroll
    for (int q = 0; q < 2; ++q) { int i = tid + 1024 * q; myk[q] = (i < nns) ? ck[i] : 0ull; myr[q] = 0; }
    for (int j = 0; j < nns8; j += 8) {
        ull t0 = ck[j], t1 = ck[j+1], t2 = ck[j+2], t3 = ck[j+3];
        ull t4 = ck[j+4], t5 = ck[j+5], t6 = ck[j+6], t7 = ck[j+7];
#pragma unroll
        for (int q = 0; q < 2; ++q) {
            myr[q] += ((t0 > myk[q]) ? 1 : 0) + ((t1 > myk[q]) ? 1 : 0)
                    + ((t2 > myk[q]) ? 1 : 0) + ((t3 > myk[q]) ? 1 : 0)
                    + ((t4 > myk[q]) ? 1 : 0) + ((t5 > myk[q]) ? 1 : 0)
                    + ((t6 > myk[q]) ? 1 : 0) + ((t7 > myk[q]) ? 1 : 0);
        }
    }
#pragma unroll
    for (int q = 0; q < 2; ++q) {
        int i = tid + 1024 * q;
        if (i < nns && myr[q] < KTOP) {
            uint32_t idx = ~(uint32_t)myk[q];
            int r = myr[q];
            int c = idx / OHW, rr = idx % OHW, s = rr / OH, t = rr % OH;
            uint32_t pk = (uint32_t)((c << 12) | (s << 6) | t);
            ns_pack[b * KTOP + r] = make_uint4(idx, __float_as_uint(cg_l[i]), pk, 0u);
        }
    }
}

// ---------------- fused attempt: selection + recon + err (R2-exact) + out-zero ----
__global__ __launch_bounds__(512) void k_att2(
    const float* __restrict__ Y, const float* __restrict__ W,
    const int* __restrict__ support_cnt, const ull* __restrict__ sup_iv,
    const ull* __restrict__ sup_gp, const uint4* __restrict__ ns_pack,
    const ull* __restrict__ kb_all,
    uint32_t* __restrict__ sel_idx, float* __restrict__ sel_val, double* __restrict__ err,
    float* __restrict__ outz, int zf)
{
    int a = blockIdx.x, b = blockIdx.y, tid = threadIdx.x;
    int lane = tid & 63, wid = tid >> 6;
    float alpha = ldexpf(1.f, -a);
    int n = support_cnt[b];

    __shared__ float recon[64 * RSTRIDE];  // 18 KB
    __shared__ ull kA[KTOP];               // NS keys, descending (rank-sorted input)
    __shared__ ull s_pv[KTOP];             // lo32 = pk, hi32 = val bits (by rank)
    __shared__ uint32_t s_idx[KTOP];       // idx by rank
    __shared__ double redd[8];

    // phase 0: halves load their (packed) pools; NS publishes kA
    uint32_t myi = 0, mypk = 0;
    float myv = 0.f;
    ull myk = 0;
    if (tid < KTOP) {               // NS-pool half: one uint4 load
        uint4 np = ns_pack[b * KTOP + tid];
        myi = np.x;
        myv = alpha * __uint_as_float(np.y);
        mypk = np.z;
        myk = ((ull)(__float_as_uint(myv) & 0x7fffffffu) << 32) | (ull)(uint32_t)(~myi);
        kA[tid] = myk;
    } else {                        // support-pool half: two ull loads
        int t2 = tid - KTOP;
        ull gp = sup_gp[b * KTOP + t2];
        ull iv = sup_iv[b * KTOP + t2];
        if (t2 < n) {
            myi = (uint32_t)iv;
            myv = fmaf(alpha, __uint_as_float((uint32_t)(gp >> 32)),
                       __uint_as_float((uint32_t)(iv >> 32)));
            mypk = (uint32_t)gp;
        } else {
            myi = (uint32_t)(CHW + t2);    // dummy: unique idx, |v|=0 -> never selected
            myv = 0.f; mypk = 0u;
        }
        myk = ((ull)(__float_as_uint(myv) & 0x7fffffffu) << 32) | (ull)(uint32_t)(~myi);
    }

    // hoist Y loads: needed only after barrier 3 -> full-kernel latency hiding
    const float4* Y4 = (const float4*)(Y + b * IMG2);
    float4 y0 = Y4[tid * 2], y1 = Y4[tid * 2 + 1];

    for (int i = tid; i < 64 * RSTRIDE; i += 512) recon[i] = 0.f;
    __syncthreads();   // barrier 1: kA + zeroed recon visible

    // count vs support keys: wave-uniform global reads (scalar-load path)
    const ull* __restrict__ kb = kb_all + ((size_t)a * NB + b) * KTOP;
    int cb0 = 0, cb1 = 0;
    for (int j = 0; j < KTOP; j += 8) {
        ull t0 = kb[j],     t1 = kb[j + 1], t2 = kb[j + 2], t3 = kb[j + 3];
        ull t4 = kb[j + 4], t5 = kb[j + 5], t6 = kb[j + 6], t7 = kb[j + 7];
        cb0 += ((t0 > myk) ? 1 : 0) + ((t1 > myk) ? 1 : 0)
             + ((t2 > myk) ? 1 : 0) + ((t3 > myk) ? 1 : 0);
        cb1 += ((t4 > myk) ? 1 : 0) + ((t5 > myk) ? 1 : 0)
             + ((t6 > myk) ? 1 : 0) + ((t7 > myk) ? 1 : 0);
    }
    int cb = cb0 + cb1;
    int rank;
    if (tid < KTOP) {
        rank = tid + cb;                       // kA sorted desc, unique keys
    } else {
        int lo = 0, hi = KTOP;                 // count of kA > myk (binsearch, desc)
        while (lo < hi) { int mid = (lo + hi) >> 1; if (kA[mid] > myk) lo = mid + 1; else hi = mid; }
        rank = lo + cb;
    }
    if (rank < KTOP) {
        s_pv[rank] = ((ull)__float_as_uint(myv) << 32) | (ull)mypk;
        s_idx[rank] = myi;
    }
    __syncthreads();   // barrier 2: selection complete (LDS only; no store drain)

    // scatter: thread handles candidates i = wid + 8k (k=0..31), tap = lane fixed.
    // 4-deep pipeline: prefetch next group's (pk,val) + W while committing current.
    {
        int p = lane >> 3, q = lane & 7;
        ull pv[4]; float wv[4];
#pragma unroll
        for (int j = 0; j < 4; ++j) pv[j] = s_pv[wid + 8 * j];
#pragma unroll
        for (int j = 0; j < 4; ++j) wv[j] = W[(((uint32_t)pv[j]) >> 12) * 64 + lane];
#pragma unroll
        for (int k4 = 0; k4 < 32; k4 += 4) {
            ull npv[4] = {0, 0, 0, 0}; float nwv[4] = {0.f, 0.f, 0.f, 0.f};
            if (k4 + 4 < 32) {
#pragma unroll
                for (int j = 0; j < 4; ++j) npv[j] = s_pv[wid + 8 * (k4 + 4 + j)];
#pragma unroll
                for (int j = 0; j < 4; ++j) nwv[j] = W[(((uint32_t)npv[j]) >> 12) * 64 + lane];
            }
#pragma unroll
            for (int j = 0; j < 4; ++j) {
                uint32_t pk = (uint32_t)pv[j];
                float val = __uint_as_float((uint32_t)(pv[j] >> 32));
                int s = (pk >> 6) & 63, t = pk & 63;
                atomicAdd(&recon[(s + p) * RSTRIDE + (t + q)], val * wv[j]);
            }
#pragma unroll
            for (int j = 0; j < 4; ++j) { pv[j] = npv[j]; wv[j] = nwv[j]; }
        }
    }
    __syncthreads();   // barrier 3

    double accd = 0.0;
    {
        int idx0 = tid * 2;
        const float* rr = &recon[(idx0 >> 4) * RSTRIDE + (idx0 & 15) * 4];
        float d0 = y0.x - rr[0]; accd += (double)d0 * (double)d0;
        float d1 = y0.y - rr[1]; accd += (double)d1 * (double)d1;
        float d2 = y0.z - rr[2]; accd += (double)d2 * (double)d2;
        float d3 = y0.w - rr[3]; accd += (double)d3 * (double)d3;
        int idx1 = tid * 2 + 1;
        rr = &recon[(idx1 >> 4) * RSTRIDE + (idx1 & 15) * 4];
        float e0 = y1.x - rr[0]; accd += (double)e0 * (double)e0;
        float e1 = y1.y - rr[1]; accd += (double)e1 * (double)e1;
        float e2 = y1.z - rr[2]; accd += (double)e2 * (double)e2;
        float e3 = y1.w - rr[3]; accd += (double)e3 * (double)e3;
    }
    for (int d = 32; d > 0; d >>= 1) accd += __shfl_xor(accd, d, 64);
    if (lane == 0) redd[wid] = accd;
    __syncthreads();   // barrier 4
    if (tid == 0) {
        double e = 0.0;
#pragma unroll
        for (int w2 = 0; w2 < 8; ++w2) e += redd[w2];
        err[a * NB + b] = e;
    }

    // tail: coalesced sel writes (rank->tid), no barrier after -> drain at endpgm
    if (tid < KTOP) {
        size_t o = ((size_t)a * NB + b) * KTOP;
        ull pvt = s_pv[tid];
        sel_idx[o + tid] = s_idx[tid];
        sel_val[o + tid] = __uint_as_float((uint32_t)(pvt >> 32));
    }

    // fused out-zero on the final iteration (att2 never reads g/out; next dispatch
    // k_scatter2 sees zeros via the dispatch boundary)
    if (zf) {
        float4* o4 = (float4*)outz;
        size_t fb = (size_t)a * NB + b;
        for (size_t i = fb * 512 + tid; i < (size_t)NB * CHW / 4; i += (size_t)NATT * NB * 512)
            o4[i] = make_float4(0.f, 0.f, 0.f, 0.f);
    }
}

// ---------------- final: fused alpha-select + scatter ----------------
__global__ __launch_bounds__(256) void k_scatter2(
    const double* __restrict__ l2f, const double* __restrict__ errv,
    const uint32_t* __restrict__ sel_idx, const float* __restrict__ sel_val,
    float* __restrict__ out)
{
    int b = blockIdx.x, tid = threadIdx.x;
    __shared__ double red2[NATT + 1];
    __shared__ int a_sh;
    if (tid < NATT) {
        double e = 0.0;
#pragma unroll 8
        for (int b2 = 0; b2 < NB; ++b2) e += errv[tid * NB + b2];
        red2[tid] = e;
    } else if (tid == NATT) {
        double l2 = 0.0;
#pragma unroll 8
        for (int b2 = 0; b2 < NB; ++b2) l2 += l2f[b2];
        red2[NATT] = l2;
    }
    __syncthreads();
    if (tid == 0) {
        double l2 = red2[NATT];
        int sel = NATT - 1;
        for (int a2 = 0; a2 < NATT; ++a2) if (red2[a2] < l2) { sel = a2; break; }
        a_sh = sel;
    }
    __syncthreads();
    size_t o = ((size_t)a_sh * NB + b) * KTOP;
    out[(size_t)b * CHW + sel_idx[o + tid]] = sel_val[o + tid];
}

// ---------------- host ----------------
static size_t align256(size_t x) { return (x + 255) & ~(size_t)255; }

extern "C" void kernel_launch(void* const* d_in, const int* in_sizes, int n_in,
                              void* d_out, int out_size, void* d_ws, size_t ws_size,
                              hipStream_t stream)
{
    const float* Y = (const float*)d_in[0];   // (32,1,64,64)
    const float* W = (const float*)d_in[1];   // (128,1,8,8), normalized
    float* out = (float*)d_out;               // (32,128,57,57) — doubles as dense g

    char* p = (char*)d_ws;
    size_t off = 0;
    auto carve = [&](size_t bytes) { void* r = p + off; off = align256(off + bytes); return r; };
    float*    Rg          = (float*)   carve(NB * IMG2 * sizeof(float));
    uint32_t* hist        = (uint32_t*)carve((size_t)NB * NBUCK * sizeof(uint32_t));
    uint32_t* thr         = (uint32_t*)carve(NB * sizeof(uint32_t));
    int*      cand_cnt    = (int*)     carve(NB * NS * sizeof(int));
    double*   l2part      = (double*)  carve(2 * NB * sizeof(double));
    double*   err         = (double*)  carve((size_t)NATT * NB * sizeof(double));
    int*      support_cnt = (int*)     carve(NB * sizeof(int));
    ull*      sup_iv      = (ull*)     carve((size_t)NB * KTOP * sizeof(ull));
    uint32_t* sel_idx     = (uint32_t*)carve((size_t)NATT * NB * KTOP * sizeof(uint32_t));
    float*    sel_val     = (float*)   carve((size_t)NATT * NB * KTOP * sizeof(float));
    uint32_t* cand_idx    = (uint32_t*)carve((size_t)NB * NS * SCAP * sizeof(uint32_t));
    float*    cand_g      = (float*)   carve((size_t)NB * NS * SCAP * sizeof(float));
    uint4*    ns_pack     = (uint4*)   carve((size_t)NB * KTOP * sizeof(uint4));
    ull*      sup_gp      = (ull*)     carve((size_t)NB * KTOP * sizeof(ull));
    ull*      kb_all      = (ull*)     carve((size_t)NATT * NB * KTOP * sizeof(ull));
    (void)ws_size; (void)in_sizes; (void)n_in; (void)out_size;

    k_init<<<1, 64, 0, stream>>>(support_cnt);
    for (int t = 0; t < 3; ++t) {
        double* l2cur  = l2part + (t & 1) * NB;
        double* l2prev = l2part + ((t + 1) & 1) * NB;
        k_resid<<<NB + NZB, 256, 0, stream>>>(Y, W, l2prev, err, sel_idx, sel_val, t,
                                              support_cnt, sup_iv, Rg, l2cur, hist, cand_cnt);
        k_conv<<<dim3(NB, 16), 256, 0, stream>>>(Rg, W, out, hist);
        k_thresh<<<NB, 256, 0, stream>>>(hist, thr);
        k_collect<<<dim3((CHW / 4 + 255) / 256, NB), 256, 0, stream>>>(out, thr, cand_cnt, cand_idx, cand_g);
        k_suppg<<<NB, 1024, 0, stream>>>(out, support_cnt, sup_iv,
                                         cand_cnt, cand_idx, cand_g,
                                         ns_pack, sup_gp, kb_all);
        k_att2<<<dim3(NATT, NB), 512, 0, stream>>>(Y, W, support_cnt, sup_iv,
                                                   sup_gp, ns_pack, kb_all,
                                                   sel_idx, sel_val, err,
                                                   out, (t == 2) ? 1 : 0);
    }
    // final selection fused into scatter; l2 of iter 2 lives in buffer (2&1)=0
    k_scatter2<<<NB, 256, 0, stream>>>(l2part, err, sel_idx, sel_val, out);
}